// Round 1
// baseline (2979.513 us; speedup 1.0000x reference)
//
#include <hip/hip_runtime.h>
#include <math.h>

#define PI_F 3.14159265358979323846f

namespace {
constexpr int B_ = 8;
constexpr int L_ = 3072;
constexpr int S_ = 3072;
constexpr int H_ = 8;
constexpr int NF = 544;          // fused projection width: 512 (main) + 16 (omega) + 16 (theta)
constexpr int NSC = 8;           // s-chunks for layer-0 attention
constexpr int SCHUNK = S_ / NSC; // 384
}

// ---------------------------------------------------------------------------
// misc small kernels
// ---------------------------------------------------------------------------
__global__ void init_pen(float* pen) {
  if (threadIdx.x < 16) pen[threadIdx.x] = 0.f;
}

__global__ void write_pen(const float* __restrict__ pen, float* __restrict__ out) {
  if (threadIdx.x == 0) out[12582912] = pen[0];
  if (threadIdx.x == 1) out[12582913] = pen[1];
}

// Pack Wmain[512,512] | Wom[512,16] | Wth[512,16] -> Wcat[512,544]; same for bias.
__global__ void pack_w(const float* __restrict__ Wm, const float* __restrict__ Wo_,
                       const float* __restrict__ Wt, const float* __restrict__ bm,
                       const float* __restrict__ bo_, const float* __restrict__ bt,
                       float* __restrict__ Wcat, float* __restrict__ bcat) {
  int gid = blockIdx.x * 256 + threadIdx.x;
  if (gid < 512 * 544) {
    int k = gid / 544, n = gid % 544;
    float v;
    if (n < 512) v = Wm[(size_t)k * 512 + n];
    else if (n < 528) v = Wo_[k * 16 + (n - 512)];
    else v = Wt[k * 16 + (n - 528)];
    Wcat[gid] = v;
  }
  if (gid < 544) {
    float v;
    if (gid < 512) v = bm[gid];
    else if (gid < 528) v = bo_[gid - 512];
    else v = bt[gid - 528];
    bcat[gid] = v;
  }
}

// ---------------------------------------------------------------------------
// Generic K=512 fp32 GEMM: C[M,N] = act(A[M,512] @ W[512,N] + bias[N])
// act=1: cols 512..527 -> relu, cols 528..543 -> tanh(x)*pi (fused om/th proj)
// BM=64, BN=64, BK=16, 256 threads, 4x4 accum per thread.
// ---------------------------------------------------------------------------
__global__ __launch_bounds__(256)
void gemm_k512(const float* __restrict__ A, const float* __restrict__ W,
               const float* __restrict__ bias, float* __restrict__ C,
               int M, int N, int act) {
  __shared__ float As[16][68];   // [k][m]
  __shared__ float Ws_[16][68];  // [k][n]
  const int tid = threadIdx.x;
  const int tx = tid & 15, ty = tid >> 4;
  const int m0 = blockIdx.y * 64, n0 = blockIdx.x * 64;

  float acc[4][4];
#pragma unroll
  for (int i = 0; i < 4; ++i)
#pragma unroll
    for (int j = 0; j < 4; ++j) acc[i][j] = 0.f;

  const int arow = tid >> 2;          // 0..63
  const int acol4 = (tid & 3) * 4;    // 0,4,8,12
  const int wrow = tid >> 4;          // 0..15
  const int wcol4 = (tid & 15) * 4;   // 0..60

  for (int k0 = 0; k0 < 512; k0 += 16) {
    // A tile
    float4 av = make_float4(0.f, 0.f, 0.f, 0.f);
    int gm = m0 + arow;
    if (gm < M) av = *(const float4*)(A + (size_t)gm * 512 + k0 + acol4);
    As[acol4 + 0][arow] = av.x;
    As[acol4 + 1][arow] = av.y;
    As[acol4 + 2][arow] = av.z;
    As[acol4 + 3][arow] = av.w;
    // W tile
    float4 wv;
    int gn = n0 + wcol4;
    if (gn + 3 < N) {
      wv = *(const float4*)(W + (size_t)(k0 + wrow) * N + gn);
    } else {
      float tmp[4] = {0.f, 0.f, 0.f, 0.f};
      for (int u = 0; u < 4; ++u)
        if (gn + u < N) tmp[u] = W[(size_t)(k0 + wrow) * N + gn + u];
      wv = make_float4(tmp[0], tmp[1], tmp[2], tmp[3]);
    }
    *(float4*)&Ws_[wrow][wcol4] = wv;
    __syncthreads();
#pragma unroll
    for (int k = 0; k < 16; ++k) {
      float4 a4 = *(const float4*)&As[k][ty * 4];
      float4 b4 = *(const float4*)&Ws_[k][tx * 4];
      float a[4] = {a4.x, a4.y, a4.z, a4.w};
      float b[4] = {b4.x, b4.y, b4.z, b4.w};
#pragma unroll
      for (int i = 0; i < 4; ++i)
#pragma unroll
        for (int j = 0; j < 4; ++j) acc[i][j] = fmaf(a[i], b[j], acc[i][j]);
    }
    __syncthreads();
  }

#pragma unroll
  for (int i = 0; i < 4; ++i) {
    int gm = m0 + ty * 4 + i;
    if (gm >= M) continue;
#pragma unroll
    for (int j = 0; j < 4; ++j) {
      int gn = n0 + tx * 4 + j;
      if (gn >= N) continue;
      float v = acc[i][j] + bias[gn];
      if (act && gn >= 512) v = (gn < 528) ? fmaxf(v, 0.f) : tanhf(v) * PI_F;
      C[(size_t)gm * N + gn] = v;
    }
  }
}

// ---------------------------------------------------------------------------
// Build Qr0 [8h][96l][128d] from QF0 [96][544] (layer-0 q-side, no batch).
// d = m*64 + c*16 + e ; partner c^1 ; signs (-,+,+,-) ; qpos = l/96
// ---------------------------------------------------------------------------
__global__ __launch_bounds__(256)
void build_qr0(const float* __restrict__ QF0, float* __restrict__ Qr0) {
  const int l = blockIdx.x;  // 0..95
  const float* row = QF0 + (size_t)l * NF;
  __shared__ float2 trig[8][2];
  const int tid = threadIdx.x;
  if (tid < 16) {
    int h = tid >> 1, m = tid & 1;
    float om = row[512 + h * 2 + m], th = row[528 + h * 2 + m];
    float qa = fmaf(om, (float)l / 96.f, th);
    trig[h][m] = make_float2(cosf(qa), sinf(qa));
  }
  __syncthreads();
  for (int idx = tid; idx < 1024; idx += 256) {
    int h = idx >> 7, d = idx & 127;
    int m = d >> 6, r = d & 63, c = r >> 4, e = r & 15;
    float qc = row[h * 64 + c * 16 + e];
    float qp = row[h * 64 + (c ^ 1) * 16 + e];
    float2 tg = trig[h][m];
    float sgn = (c == 0 || c == 3) ? -1.f : 1.f;
    Qr0[((size_t)h * 96 + l) * 128 + d] = fmaf(qc, tg.x, sgn * qp * tg.y);
  }
}

// ---------------------------------------------------------------------------
// Build Kr1 [b*8+h][96s][128d] from KF1 [768][544] (layer-1 k-side).
// partner c^2 ; signs (-,-,+,+) ; kpos = s/96
// ---------------------------------------------------------------------------
__global__ __launch_bounds__(256)
void build_kr1(const float* __restrict__ KF1, float* __restrict__ Kr1) {
  const int rs = blockIdx.x;  // b*96+s
  const int b = rs / 96, s = rs % 96;
  const float* row = KF1 + (size_t)rs * NF;
  __shared__ float2 trig[8][2];
  const int tid = threadIdx.x;
  if (tid < 16) {
    int h = tid >> 1, m = tid & 1;
    float om = row[512 + h * 2 + m], th = row[528 + h * 2 + m];
    float ka = fmaf(om, (float)s / 96.f, th);
    trig[h][m] = make_float2(cosf(ka), sinf(ka));
  }
  __syncthreads();
  for (int idx = tid; idx < 1024; idx += 256) {
    int h = idx >> 7, d = idx & 127;
    int m = d >> 6, r = d & 63, c = r >> 4, e = r & 15;
    float kc = row[h * 64 + c * 16 + e];
    float kp = row[h * 64 + (c ^ 2) * 16 + e];
    float2 tg = trig[h][m];
    float sgn = (c < 2) ? -1.f : 1.f;
    Kr1[(((size_t)(b * 8 + h)) * 96 + s) * 128 + d] = fmaf(kc, tg.x, sgn * kp * tg.y);
  }
}

// ---------------------------------------------------------------------------
// Layer-0 attention stage 1: grid (16=sc*2+lhalf, 8h, 8b), 256 threads.
// Per block: 48 q-rows, one 384-wide s-chunk. Logits are tiny -> exp without
// running max; partial (sum_exp, sum exp*V) are linear and combined in stage 2.
// ---------------------------------------------------------------------------
__global__ __launch_bounds__(256)
void attn0_stage1(const float* __restrict__ KF0, const float* __restrict__ V0,
                  const float* __restrict__ Qr0, float* __restrict__ accP,
                  float* __restrict__ sumP) {
  const int sc = blockIdx.x >> 1;
  const int l0 = (blockIdx.x & 1) * 48;
  const int h = blockIdx.y;
  const int b = blockIdx.z;
  const int tid = threadIdx.x;

  __shared__ float Qrs[48][132];
  __shared__ float Krs[32][132];
  __shared__ float Vs[32][68];
  __shared__ float Pt[48][33];
  __shared__ float2 trig[32][2];

  const float* Qh = Qr0 + ((size_t)h * 96 + l0) * 128;
  for (int idx = tid; idx < 48 * 32; idx += 256) {
    int l = idx >> 5, d4 = idx & 31;
    *(float4*)&Qrs[l][d4 * 4] = *(const float4*)(Qh + (size_t)l * 128 + d4 * 4);
  }

  float acc[12];
#pragma unroll
  for (int i = 0; i < 12; ++i) acc[i] = 0.f;
  float sacc = 0.f;
  const int s0 = sc * SCHUNK;

  for (int t = 0; t < SCHUNK; t += 32) {
    __syncthreads();
    if (tid < 64) {
      int s = tid >> 1, m = tid & 1;
      int sg = s0 + t + s;
      const float* row = KF0 + (size_t)(b * S_ + sg) * NF;
      float om = row[512 + h * 2 + m];
      float th = row[528 + h * 2 + m];
      float ka = fmaf(om, (float)sg / (float)S_, th);
      trig[s][m] = make_float2(cosf(ka), sinf(ka));
    }
    __syncthreads();
    for (int idx = tid; idx < 32 * 128; idx += 256) {
      int s = idx >> 7, d = idx & 127;
      int m = d >> 6, r = d & 63, c = r >> 4, e = r & 15;
      int sg = s0 + t + s;
      const float* row = KF0 + (size_t)(b * S_ + sg) * NF + h * 64;
      float kc = row[c * 16 + e];
      float kp = row[(c ^ 2) * 16 + e];
      float2 tg = trig[s][m];
      float sgn = (c < 2) ? -1.f : 1.f;
      Krs[s][d] = fmaf(kc, tg.x, sgn * kp * tg.y);
    }
    for (int idx = tid; idx < 32 * 64; idx += 256) {
      int s = idx >> 6, d = idx & 63;
      int sg = s0 + t + s;
      Vs[s][d] = V0[(size_t)(b * S_ + sg) * 512 + h * 64 + d];
    }
    __syncthreads();
    {
      int sl = tid & 31, lg = tid >> 5;
#pragma unroll
      for (int i = 0; i < 6; ++i) {
        int l = lg + 8 * i;
        float dot = 0.f;
#pragma unroll
        for (int j = 0; j < 32; ++j) {
          float4 q = *(const float4*)&Qrs[l][j * 4];
          float4 kk = *(const float4*)&Krs[sl][j * 4];
          dot = fmaf(q.x, kk.x, dot);
          dot = fmaf(q.y, kk.y, dot);
          dot = fmaf(q.z, kk.z, dot);
          dot = fmaf(q.w, kk.w, dot);
        }
        Pt[l][sl] = __expf(dot * (1.f / 16.f));  // /M(2) * 1/sqrt(64)
      }
    }
    __syncthreads();
    if (tid < 48) {
      float ssum = 0.f;
#pragma unroll
      for (int s = 0; s < 32; ++s) ssum += Pt[tid][s];
      sacc += ssum;
    }
    {
      int d = tid & 63, lg2 = tid >> 6;
#pragma unroll
      for (int i = 0; i < 12; ++i) {
        int l = lg2 + 4 * i;
        float a = 0.f;
#pragma unroll
        for (int s = 0; s < 32; ++s) a = fmaf(Pt[l][s], Vs[s][d], a);
        acc[i] += a;
      }
    }
  }
  __syncthreads();
  const int bh = b * 8 + h;
  const size_t pbase = ((size_t)bh * NSC + sc) * 96;
  {
    int d = tid & 63, lg2 = tid >> 6;
#pragma unroll
    for (int i = 0; i < 12; ++i) {
      int l = l0 + lg2 + 4 * i;
      accP[(pbase + l) * 64 + d] = acc[i];
    }
  }
  if (tid < 48) sumP[pbase + l0 + tid] = sacc;
}

// Stage 2: combine the NSC chunk partials -> attn0 [b*96+l][h*64+d]
__global__ __launch_bounds__(256)
void attn0_stage2(const float* __restrict__ accP, const float* __restrict__ sumP,
                  float* __restrict__ attn0) {
  const int l = blockIdx.x, b = blockIdx.y;
  const int tid = threadIdx.x;
  for (int e = tid; e < 512; e += 256) {
    int h = e >> 6, d = e & 63;
    size_t base = ((size_t)(b * 8 + h)) * NSC * 96;
    float num = 0.f, den = 0.f;
    for (int scv = 0; scv < NSC; ++scv) {
      size_t pb = base + (size_t)scv * 96 + l;
      num += accP[pb * 64 + d];
      den += sumP[pb];
    }
    attn0[((size_t)(b * 96 + l)) * 512 + e] = num / den;
  }
}

// ---------------------------------------------------------------------------
// trend_norm: moving_avg(k=25, edge-replicated) -> LayerNorm(seasonal) + trend
// grid (96, 8), 256 threads, each thread 2 channels.
// ---------------------------------------------------------------------------
__global__ __launch_bounds__(256)
void trend_norm(const float* __restrict__ y, const float* __restrict__ g,
                const float* __restrict__ be, float* __restrict__ outp) {
  const int t = blockIdx.x, b = blockIdx.y;
  const int tid = threadIdx.x;
  __shared__ float red[256];
  __shared__ float red2[256];
  float seas[2], trend[2];
  float lsum = 0.f, lsum2 = 0.f;
#pragma unroll
  for (int u = 0; u < 2; ++u) {
    int d = tid + u * 256;
    float tr = 0.f;
    for (int j = -12; j <= 12; ++j) {
      int tt = t + j;
      tt = tt < 0 ? 0 : (tt > 95 ? 95 : tt);
      tr += y[((size_t)(b * 96 + tt)) * 512 + d];
    }
    tr *= (1.f / 25.f);
    float x = y[((size_t)(b * 96 + t)) * 512 + d];
    float se = x - tr;
    seas[u] = se;
    trend[u] = tr;
    lsum += se;
    lsum2 += se * se;
  }
  red[tid] = lsum;
  red2[tid] = lsum2;
  __syncthreads();
  for (int off = 128; off > 0; off >>= 1) {
    if (tid < off) {
      red[tid] += red[tid + off];
      red2[tid] += red2[tid + off];
    }
    __syncthreads();
  }
  float mu = red[0] / 512.f;
  float var = red2[0] / 512.f - mu * mu;
  float rs = rsqrtf(var + 1e-5f);
#pragma unroll
  for (int u = 0; u < 2; ++u) {
    int d = tid + u * 256;
    outp[((size_t)(b * 96 + t)) * 512 + d] = (seas[u] - mu) * rs * g[d] + be[d] + trend[u];
  }
}

// ---------------------------------------------------------------------------
// Penalty: sum(diff(om, axis=seq)^2) and sum(th^2) over a fused proj buffer.
// base rows [nb*R][544]; om at cols 512..527, th at 528..543.
// ---------------------------------------------------------------------------
__global__ __launch_bounds__(256)
void penalty(const float* __restrict__ base, int R, int nb, float mult,
             float* __restrict__ pen) {
  const int tid = threadIdx.x;
  size_t gid = (size_t)blockIdx.x * 256 + tid;
  size_t total = (size_t)nb * R * 16;
  float omv = 0.f, thv = 0.f;
  if (gid < total) {
    int j = (int)(gid & 15);
    size_t row = gid >> 4;
    int s = (int)(row % R);
    const float* r0 = base + row * NF;
    float th = r0[528 + j];
    thv = th * th;
    if (s < R - 1) {
      float d = r0[NF + 512 + j] - r0[512 + j];
      omv = d * d;
    }
  }
  __shared__ float ro[256], rt[256];
  ro[tid] = omv;
  rt[tid] = thv;
  __syncthreads();
  for (int off = 128; off > 0; off >>= 1) {
    if (tid < off) {
      ro[tid] += ro[tid + off];
      rt[tid] += rt[tid + off];
    }
    __syncthreads();
  }
  if (tid == 0) {
    atomicAdd(pen + 0, mult * ro[0]);
    atomicAdd(pen + 1, mult * rt[0]);
  }
}

// ---------------------------------------------------------------------------
// Layer-1 attention: grid (64 ltiles of 48, 8h, 8b), softmax over 96 keys.
// Qr built on the fly from QF1; Kr1/V1 staged in 32-row s-tiles.
// ---------------------------------------------------------------------------
__global__ __launch_bounds__(256)
void attn1_kernel(const float* __restrict__ QF1, const float* __restrict__ Kr1,
                  const float* __restrict__ V1, float* __restrict__ attn1) {
  const int lt = blockIdx.x;
  const int h = blockIdx.y, b = blockIdx.z;
  const int l0 = lt * 48;
  const int tid = threadIdx.x;

  __shared__ float Qrs[48][132];
  __shared__ float Krs[32][132];
  __shared__ float Vs[32][68];
  __shared__ float Pt[48][33];
  __shared__ float2 trigq[48][2];
  __shared__ float sums[48];

  if (tid < 96) {
    int l = tid >> 1, m = tid & 1;
    int lg = l0 + l;
    const float* row = QF1 + (size_t)(b * L_ + lg) * NF;
    float om = row[512 + h * 2 + m];
    float th = row[528 + h * 2 + m];
    float qa = fmaf(om, (float)lg / (float)L_, th);
    trigq[l][m] = make_float2(cosf(qa), sinf(qa));
  }
  __syncthreads();
  for (int idx = tid; idx < 48 * 128; idx += 256) {
    int l = idx >> 7, d = idx & 127;
    int m = d >> 6, r = d & 63, c = r >> 4, e = r & 15;
    const float* row = QF1 + (size_t)(b * L_ + l0 + l) * NF + h * 64;
    float qc = row[c * 16 + e];
    float qp = row[(c ^ 1) * 16 + e];
    float2 tg = trigq[l][m];
    float sgn = (c == 0 || c == 3) ? -1.f : 1.f;
    Qrs[l][d] = fmaf(qc, tg.x, sgn * qp * tg.y);
  }

  float acc[12];
#pragma unroll
  for (int i = 0; i < 12; ++i) acc[i] = 0.f;
  float sacc = 0.f;
  const float* Krb = Kr1 + (size_t)(b * 8 + h) * 96 * 128;

  for (int t = 0; t < 96; t += 32) {
    __syncthreads();
    for (int idx = tid; idx < 32 * 32; idx += 256) {
      int s = idx >> 5, d4 = idx & 31;
      *(float4*)&Krs[s][d4 * 4] = *(const float4*)(Krb + (size_t)(t + s) * 128 + d4 * 4);
    }
    for (int idx = tid; idx < 32 * 64; idx += 256) {
      int s = idx >> 6, d = idx & 63;
      Vs[s][d] = V1[(size_t)(b * 96 + t + s) * 512 + h * 64 + d];
    }
    __syncthreads();
    {
      int sl = tid & 31, lg = tid >> 5;
#pragma unroll
      for (int i = 0; i < 6; ++i) {
        int l = lg + 8 * i;
        float dot = 0.f;
#pragma unroll
        for (int j = 0; j < 32; ++j) {
          float4 q = *(const float4*)&Qrs[l][j * 4];
          float4 kk = *(const float4*)&Krs[sl][j * 4];
          dot = fmaf(q.x, kk.x, dot);
          dot = fmaf(q.y, kk.y, dot);
          dot = fmaf(q.z, kk.z, dot);
          dot = fmaf(q.w, kk.w, dot);
        }
        Pt[l][sl] = __expf(dot * (1.f / 16.f));
      }
    }
    __syncthreads();
    if (tid < 48) {
      float ssum = 0.f;
#pragma unroll
      for (int s = 0; s < 32; ++s) ssum += Pt[tid][s];
      sacc += ssum;
    }
    {
      int d = tid & 63, lg2 = tid >> 6;
#pragma unroll
      for (int i = 0; i < 12; ++i) {
        int l = lg2 + 4 * i;
        float a = 0.f;
#pragma unroll
        for (int s = 0; s < 32; ++s) a = fmaf(Pt[l][s], Vs[s][d], a);
        acc[i] += a;
      }
    }
  }
  if (tid < 48) sums[tid] = sacc;
  __syncthreads();
  {
    int d = tid & 63, lg2 = tid >> 6;
#pragma unroll
    for (int i = 0; i < 12; ++i) {
      int l = lg2 + 4 * i;
      attn1[(size_t)(b * L_ + l0 + l) * 512 + h * 64 + d] = acc[i] / sums[l];
    }
  }
}

// ---------------------------------------------------------------------------
extern "C" void kernel_launch(void* const* d_in, const int* in_sizes, int n_in,
                              void* d_out, int out_size, void* d_ws, size_t ws_size,
                              hipStream_t stream) {
  (void)in_sizes; (void)n_in; (void)out_size; (void)ws_size;
  const float* queries = (const float*)d_in[0];
  const float* keys = (const float*)d_in[1];
  const float* values = (const float*)d_in[2];
  const float* Wq = (const float*)d_in[3];
  const float* bq = (const float*)d_in[4];
  const float* Wk = (const float*)d_in[5];
  const float* bk = (const float*)d_in[6];
  const float* Wv = (const float*)d_in[7];
  const float* bv = (const float*)d_in[8];
  const float* Wqo = (const float*)d_in[9];
  const float* bqo = (const float*)d_in[10];
  const float* Wko = (const float*)d_in[11];
  const float* bko = (const float*)d_in[12];
  const float* Wqt = (const float*)d_in[13];
  const float* bqt = (const float*)d_in[14];
  const float* Wkt = (const float*)d_in[15];
  const float* bkt = (const float*)d_in[16];
  const float* Wo = (const float*)d_in[17];
  const float* bo = (const float*)d_in[18];
  const float* I = (const float*)d_in[19];
  const float* ln_g = (const float*)d_in[20];
  const float* ln_b = (const float*)d_in[21];
  float* out = (float*)d_out;

  float* ws = (float*)d_ws;
  size_t off = 0;
  auto alloc = [&](size_t n) {
    float* p = ws + off;
    off += (n + 3) & ~(size_t)3;
    return p;
  };
  float* WCAT0K = alloc(512 * 544);
  float* WCAT0Q = alloc(512 * 544);
  float* WCAT1K = alloc(512 * 544);
  float* WCAT1Q = alloc(512 * 544);
  float* BCAT0K = alloc(544);
  float* BCAT0Q = alloc(544);
  float* BCAT1K = alloc(544);
  float* BCAT1Q = alloc(544);
  float* pen = alloc(16);
  float* QF0 = alloc(96 * 544);
  float* Qr0 = alloc(8 * 96 * 128);
  float* KF0 = alloc((size_t)24576 * 544);  // reused as QF1 after attention-0
  float* V0 = alloc((size_t)24576 * 512);   // reused as attn1 output
  float* attn0 = alloc(768 * 512);
  float* y0 = alloc(768 * 512);
  float* xind = alloc(768 * 512);
  float* KF1 = alloc(768 * 544);
  float* V1 = alloc(768 * 512);
  float* Kr1 = alloc((size_t)64 * 96 * 128);
  float* accP = alloc((size_t)64 * NSC * 96 * 64);
  float* sumP = alloc((size_t)64 * NSC * 96);
  float* QF1 = KF0;
  float* attn1 = V0;

  init_pen<<<1, 64, 0, stream>>>(pen);
  const int packBlocks = (512 * 544 + 255) / 256;
  pack_w<<<packBlocks, 256, 0, stream>>>(Wk, Wko, Wkt, bk, bko, bkt, WCAT0K, BCAT0K);
  pack_w<<<packBlocks, 256, 0, stream>>>(Wq, Wqo, Wqt, bq, bqo, bqt, WCAT0Q, BCAT0Q);
  pack_w<<<packBlocks, 256, 0, stream>>>(Wk + 262144, Wko + 8192, Wkt + 8192,
                                         bk + 512, bko + 16, bkt + 16, WCAT1K, BCAT1K);
  pack_w<<<packBlocks, 256, 0, stream>>>(Wq + 262144, Wqo + 8192, Wqt + 8192,
                                         bq + 512, bqo + 16, bqt + 16, WCAT1Q, BCAT1Q);

  // ---- layer 0 ----
  gemm_k512<<<dim3(9, 384), 256, 0, stream>>>(keys, WCAT0K, BCAT0K, KF0, 24576, 544, 1);
  gemm_k512<<<dim3(8, 384), 256, 0, stream>>>(values, Wv, bv, V0, 24576, 512, 0);
  gemm_k512<<<dim3(9, 2), 256, 0, stream>>>(I, WCAT0Q, BCAT0Q, QF0, 96, 544, 1);
  build_qr0<<<96, 256, 0, stream>>>(QF0, Qr0);
  penalty<<<(96 * 16 + 255) / 256, 256, 0, stream>>>(QF0, 96, 1, 8.f, pen);      // x8: broadcast batch
  penalty<<<(24576 * 16 + 255) / 256, 256, 0, stream>>>(KF0, 3072, 8, 1.f, pen);
  attn0_stage1<<<dim3(16, 8, 8), 256, 0, stream>>>(KF0, V0, Qr0, accP, sumP);
  attn0_stage2<<<dim3(96, 8), 256, 0, stream>>>(accP, sumP, attn0);
  gemm_k512<<<dim3(8, 12), 256, 0, stream>>>(attn0, Wo, bo, y0, 768, 512, 0);
  trend_norm<<<dim3(96, 8), 256, 0, stream>>>(y0, ln_g, ln_b, xind);

  // ---- layer 1 ----
  gemm_k512<<<dim3(9, 12), 256, 0, stream>>>(xind, WCAT1K, BCAT1K, KF1, 768, 544, 1);
  gemm_k512<<<dim3(8, 12), 256, 0, stream>>>(xind, Wv + 262144, bv + 512, V1, 768, 512, 0);
  build_kr1<<<768, 256, 0, stream>>>(KF1, Kr1);
  penalty<<<(768 * 16 + 255) / 256, 256, 0, stream>>>(KF1, 96, 8, 1.f, pen);
  gemm_k512<<<dim3(9, 384), 256, 0, stream>>>(queries, WCAT1Q, BCAT1Q, QF1, 24576, 544, 1);
  penalty<<<(24576 * 16 + 255) / 256, 256, 0, stream>>>(QF1, 3072, 8, 1.f, pen);
  attn1_kernel<<<dim3(64, 8, 8), 256, 0, stream>>>(QF1, Kr1, V1, attn1);
  gemm_k512<<<dim3(8, 384), 256, 0, stream>>>(attn1, Wo + 262144, bo + 512, out, 24576, 512, 0);
  write_pen<<<1, 64, 0, stream>>>(pen, out);
}

// Round 2
// 1366.687 us; speedup vs baseline: 2.1801x; 2.1801x over previous
//
#include <hip/hip_runtime.h>
#include <math.h>

#define PI_F 3.14159265358979323846f

namespace {
constexpr int B_ = 8;
constexpr int L_ = 3072;
constexpr int S_ = 3072;
constexpr int H_ = 8;
constexpr int NF = 544;          // fused projection width: 512 (main) + 16 (omega) + 16 (theta)
constexpr int NSC = 8;           // s-chunks for layer-0 attention
constexpr int SCHUNK = S_ / NSC; // 384
}

typedef __attribute__((ext_vector_type(8))) short bf16x8;
typedef __attribute__((ext_vector_type(4))) float f32x4;

__device__ inline f32x4 mfma16(bf16x8 a, bf16x8 b, f32x4 c) {
  return __builtin_amdgcn_mfma_f32_16x16x32_bf16(a, b, c, 0, 0, 0);
}

__device__ inline ushort f2bf(float f) {
  union { float f; unsigned u; } v;
  v.f = f;
  unsigned r = v.u + 0x7FFFu + ((v.u >> 16) & 1u);
  return (ushort)(r >> 16);
}

// ---------------------------------------------------------------------------
// misc small kernels
// ---------------------------------------------------------------------------
__global__ void init_pen(float* pen) {
  if (threadIdx.x < 16) pen[threadIdx.x] = 0.f;
}

__global__ void write_pen(const float* __restrict__ pen, float* __restrict__ out) {
  if (threadIdx.x == 0) out[12582912] = pen[0];
  if (threadIdx.x == 1) out[12582913] = pen[1];
}

// Pack Wmain[512,512] | Wom[512,16] | Wth[512,16] -> Wcat[512,544]; same for bias.
__global__ void pack_w(const float* __restrict__ Wm, const float* __restrict__ Wo_,
                       const float* __restrict__ Wt, const float* __restrict__ bm,
                       const float* __restrict__ bo_, const float* __restrict__ bt,
                       float* __restrict__ Wcat, float* __restrict__ bcat) {
  int gid = blockIdx.x * 256 + threadIdx.x;
  if (gid < 512 * 544) {
    int k = gid / 544, n = gid % 544;
    float v;
    if (n < 512) v = Wm[(size_t)k * 512 + n];
    else if (n < 528) v = Wo_[k * 16 + (n - 512)];
    else v = Wt[k * 16 + (n - 528)];
    Wcat[gid] = v;
  }
  if (gid < 544) {
    float v;
    if (gid < 512) v = bm[gid];
    else if (gid < 528) v = bo_[gid - 512];
    else v = bt[gid - 528];
    bcat[gid] = v;
  }
}

// ---------------------------------------------------------------------------
// Generic K=512 fp32 GEMM: C[M,N] = act(A[M,512] @ W[512,N] + bias[N])
// act=1: cols 512..527 -> relu, cols 528..543 -> tanh(x)*pi (fused om/th proj)
// ---------------------------------------------------------------------------
__global__ __launch_bounds__(256)
void gemm_k512(const float* __restrict__ A, const float* __restrict__ W,
               const float* __restrict__ bias, float* __restrict__ C,
               int M, int N, int act) {
  __shared__ float As[16][68];   // [k][m]
  __shared__ float Ws_[16][68];  // [k][n]
  const int tid = threadIdx.x;
  const int tx = tid & 15, ty = tid >> 4;
  const int m0 = blockIdx.y * 64, n0 = blockIdx.x * 64;

  float acc[4][4];
#pragma unroll
  for (int i = 0; i < 4; ++i)
#pragma unroll
    for (int j = 0; j < 4; ++j) acc[i][j] = 0.f;

  const int arow = tid >> 2;
  const int acol4 = (tid & 3) * 4;
  const int wrow = tid >> 4;
  const int wcol4 = (tid & 15) * 4;

  for (int k0 = 0; k0 < 512; k0 += 16) {
    float4 av = make_float4(0.f, 0.f, 0.f, 0.f);
    int gm = m0 + arow;
    if (gm < M) av = *(const float4*)(A + (size_t)gm * 512 + k0 + acol4);
    As[acol4 + 0][arow] = av.x;
    As[acol4 + 1][arow] = av.y;
    As[acol4 + 2][arow] = av.z;
    As[acol4 + 3][arow] = av.w;
    float4 wv;
    int gn = n0 + wcol4;
    if (gn + 3 < N) {
      wv = *(const float4*)(W + (size_t)(k0 + wrow) * N + gn);
    } else {
      float tmp[4] = {0.f, 0.f, 0.f, 0.f};
      for (int u = 0; u < 4; ++u)
        if (gn + u < N) tmp[u] = W[(size_t)(k0 + wrow) * N + gn + u];
      wv = make_float4(tmp[0], tmp[1], tmp[2], tmp[3]);
    }
    *(float4*)&Ws_[wrow][wcol4] = wv;
    __syncthreads();
#pragma unroll
    for (int k = 0; k < 16; ++k) {
      float4 a4 = *(const float4*)&As[k][ty * 4];
      float4 b4 = *(const float4*)&Ws_[k][tx * 4];
      float a[4] = {a4.x, a4.y, a4.z, a4.w};
      float b[4] = {b4.x, b4.y, b4.z, b4.w};
#pragma unroll
      for (int i = 0; i < 4; ++i)
#pragma unroll
        for (int j = 0; j < 4; ++j) acc[i][j] = fmaf(a[i], b[j], acc[i][j]);
    }
    __syncthreads();
  }

#pragma unroll
  for (int i = 0; i < 4; ++i) {
    int gm = m0 + ty * 4 + i;
    if (gm >= M) continue;
#pragma unroll
    for (int j = 0; j < 4; ++j) {
      int gn = n0 + tx * 4 + j;
      if (gn >= N) continue;
      float v = acc[i][j] + bias[gn];
      if (act && gn >= 512) v = (gn < 528) ? fmaxf(v, 0.f) : tanhf(v) * PI_F;
      C[(size_t)gm * N + gn] = v;
    }
  }
}

// ---------------------------------------------------------------------------
// Build Qr0 [8h][96l][128d] from QF0 [96][544] (layer-0 q-side, no batch).
// ---------------------------------------------------------------------------
__global__ __launch_bounds__(256)
void build_qr0(const float* __restrict__ QF0, float* __restrict__ Qr0) {
  const int l = blockIdx.x;
  const float* row = QF0 + (size_t)l * NF;
  __shared__ float2 trig[8][2];
  const int tid = threadIdx.x;
  if (tid < 16) {
    int h = tid >> 1, m = tid & 1;
    float om = row[512 + h * 2 + m], th = row[528 + h * 2 + m];
    float qa = fmaf(om, (float)l / 96.f, th);
    trig[h][m] = make_float2(cosf(qa), sinf(qa));
  }
  __syncthreads();
  for (int idx = tid; idx < 1024; idx += 256) {
    int h = idx >> 7, d = idx & 127;
    int m = d >> 6, r = d & 63, c = r >> 4, e = r & 15;
    float qc = row[h * 64 + c * 16 + e];
    float qp = row[h * 64 + (c ^ 1) * 16 + e];
    float2 tg = trig[h][m];
    float sgn = (c == 0 || c == 3) ? -1.f : 1.f;
    Qr0[((size_t)h * 96 + l) * 128 + d] = fmaf(qc, tg.x, sgn * qp * tg.y);
  }
}

// ---------------------------------------------------------------------------
// Build Kr1 [b*8+h][96s][128d] from KF1 [768][544] (layer-1 k-side).
// ---------------------------------------------------------------------------
__global__ __launch_bounds__(256)
void build_kr1(const float* __restrict__ KF1, float* __restrict__ Kr1) {
  const int rs = blockIdx.x;
  const int b = rs / 96, s = rs % 96;
  const float* row = KF1 + (size_t)rs * NF;
  __shared__ float2 trig[8][2];
  const int tid = threadIdx.x;
  if (tid < 16) {
    int h = tid >> 1, m = tid & 1;
    float om = row[512 + h * 2 + m], th = row[528 + h * 2 + m];
    float ka = fmaf(om, (float)s / 96.f, th);
    trig[h][m] = make_float2(cosf(ka), sinf(ka));
  }
  __syncthreads();
  for (int idx = tid; idx < 1024; idx += 256) {
    int h = idx >> 7, d = idx & 127;
    int m = d >> 6, r = d & 63, c = r >> 4, e = r & 15;
    float kc = row[h * 64 + c * 16 + e];
    float kp = row[h * 64 + (c ^ 2) * 16 + e];
    float2 tg = trig[h][m];
    float sgn = (c < 2) ? -1.f : 1.f;
    Kr1[(((size_t)(b * 8 + h)) * 96 + s) * 128 + d] = fmaf(kc, tg.x, sgn * kp * tg.y);
  }
}

// ---------------------------------------------------------------------------
// Layer-0 attention, MFMA version. grid (8 sc, 8 h, 8 b), 256 threads.
// Q[96,128] x K^T per 64-s tile -> exp -> P[96,64] -> PV accum [96,64].
// Partial (acc, sum) per sc combined by attn0_stage2 (logits tiny: no max).
// ---------------------------------------------------------------------------
__global__ __launch_bounds__(256)
void attn0_mfma(const float* __restrict__ KF0, const float* __restrict__ V0,
                const float* __restrict__ Qr0, float* __restrict__ accP,
                float* __restrict__ sumP) {
  const int sc = blockIdx.x, h = blockIdx.y, b = blockIdx.z;
  const int tid = threadIdx.x;
  const int wv = tid >> 6, lane = tid & 63, quad = lane >> 4, col = lane & 15;

  // +8 bf16 pad on rows -> bank stride 4 words -> 2-way aliasing (free)
  __shared__ __align__(16) ushort Qs[96][136];
  __shared__ __align__(16) ushort Ks[64][136];
  __shared__ __align__(16) ushort Vt[64][72];   // [d][s]
  __shared__ __align__(16) ushort Ps[96][72];   // [l][s]
  __shared__ float rowsum[96];
  __shared__ float2 trig[64][2];

  // stage Q (bf16) once
  const float* Qh = Qr0 + ((size_t)h * 96) * 128;
  for (int idx = tid; idx < 96 * 64; idx += 256) {
    int l = idx >> 6, d2 = (idx & 63) * 2;
    float2 q = *(const float2*)(Qh + (size_t)l * 128 + d2);
    ushort2 u;
    u.x = f2bf(q.x);
    u.y = f2bf(q.y);
    *(ushort2*)&Qs[l][d2] = u;
  }
  if (tid < 96) rowsum[tid] = 0.f;

  f32x4 oacc[6];
#pragma unroll
  for (int i = 0; i < 6; ++i) {
    f32x4 z = {0.f, 0.f, 0.f, 0.f};
    oacc[i] = z;
  }

  const int s0g = sc * SCHUNK;
  for (int t = 0; t < 6; ++t) {
    const int sb = s0g + t * 64;
    __syncthreads();  // prev PV done reading Vt/Ps; trig reusable
    if (tid < 128) {
      int s = tid >> 1, m = tid & 1;
      const float* row = KF0 + (size_t)(b * S_ + sb + s) * NF;
      float om = row[512 + h * 2 + m];
      float th = row[528 + h * 2 + m];
      float ka = fmaf(om, (float)(sb + s) * (1.f / (float)S_), th);
      trig[s][m] = make_float2(cosf(ka), sinf(ka));
    }
    __syncthreads();
    // rotated K tile -> bf16 LDS
    for (int idx = tid; idx < 64 * 128; idx += 256) {
      int s = idx >> 7, d = idx & 127;
      int m = d >> 6, r = d & 63, c = r >> 4, e = r & 15;
      const float* row = KF0 + (size_t)(b * S_ + sb + s) * NF + h * 64;
      float kc = row[c * 16 + e];
      float kp = row[(c ^ 2) * 16 + e];
      float2 tg = trig[s][m];
      float sgn = (c < 2) ? -1.f : 1.f;
      Ks[s][d] = f2bf(fmaf(kc, tg.x, sgn * kp * tg.y));
    }
    // V tile transposed -> bf16 LDS
    for (int idx = tid; idx < 64 * 64; idx += 256) {
      int s = idx >> 6, d = idx & 63;
      Vt[d][s] = f2bf(V0[(size_t)(b * S_ + sb + s) * 512 + h * 64 + d]);
    }
    __syncthreads();
    // QK^T: wave wv owns s-cols wv*16..+15; 6 m-tiles over 96 l
    bf16x8 bk[4];
#pragma unroll
    for (int k = 0; k < 4; ++k)
      bk[k] = *(const bf16x8*)&Ks[wv * 16 + col][k * 32 + quad * 8];
    f32x4 sacc[6];
#pragma unroll
    for (int mt = 0; mt < 6; ++mt) {
      f32x4 z = {0.f, 0.f, 0.f, 0.f};
      sacc[mt] = z;
#pragma unroll
      for (int k = 0; k < 4; ++k) {
        bf16x8 a = *(const bf16x8*)&Qs[mt * 16 + col][k * 32 + quad * 8];
        sacc[mt] = mfma16(a, bk[k], sacc[mt]);
      }
    }
    // exp (logits ~N(0,0.5): max-free exact), P->LDS, rowsums
#pragma unroll
    for (int mt = 0; mt < 6; ++mt) {
      float pr[4];
#pragma unroll
      for (int r = 0; r < 4; ++r) {
        float p = __expf(sacc[mt][r] * 0.0625f);  // /(M=2 * sqrt(64))
        pr[r] = p;
        Ps[mt * 16 + quad * 4 + r][wv * 16 + col] = f2bf(p);
      }
#pragma unroll
      for (int r = 0; r < 4; ++r) {
#pragma unroll
        for (int off = 1; off < 16; off <<= 1) pr[r] += __shfl_xor(pr[r], off);
      }
      if (col == 0) {
#pragma unroll
        for (int r = 0; r < 4; ++r)
          atomicAdd(&rowsum[mt * 16 + quad * 4 + r], pr[r]);
      }
    }
    __syncthreads();
    // PV: wave wv owns d-cols wv*16..+15
    bf16x8 bv0 = *(const bf16x8*)&Vt[wv * 16 + col][quad * 8];
    bf16x8 bv1 = *(const bf16x8*)&Vt[wv * 16 + col][32 + quad * 8];
#pragma unroll
    for (int mt = 0; mt < 6; ++mt) {
      bf16x8 a0 = *(const bf16x8*)&Ps[mt * 16 + col][quad * 8];
      oacc[mt] = mfma16(a0, bv0, oacc[mt]);
      bf16x8 a1 = *(const bf16x8*)&Ps[mt * 16 + col][32 + quad * 8];
      oacc[mt] = mfma16(a1, bv1, oacc[mt]);
    }
  }
  __syncthreads();
  const size_t pbase = (((size_t)(b * 8 + h)) * NSC + sc) * 96;
#pragma unroll
  for (int mt = 0; mt < 6; ++mt) {
#pragma unroll
    for (int r = 0; r < 4; ++r) {
      int l = mt * 16 + quad * 4 + r;
      accP[(pbase + l) * 64 + wv * 16 + col] = oacc[mt][r];
    }
  }
  if (tid < 96) sumP[pbase + tid] = rowsum[tid];
}

// Stage 2: combine the NSC chunk partials -> attn0 [b*96+l][h*64+d]
__global__ __launch_bounds__(256)
void attn0_stage2(const float* __restrict__ accP, const float* __restrict__ sumP,
                  float* __restrict__ attn0) {
  const int l = blockIdx.x, b = blockIdx.y;
  const int tid = threadIdx.x;
  for (int e = tid; e < 512; e += 256) {
    int h = e >> 6, d = e & 63;
    size_t base = ((size_t)(b * 8 + h)) * NSC * 96;
    float num = 0.f, den = 0.f;
    for (int scv = 0; scv < NSC; ++scv) {
      size_t pb = base + (size_t)scv * 96 + l;
      num += accP[pb * 64 + d];
      den += sumP[pb];
    }
    attn0[((size_t)(b * 96 + l)) * 512 + e] = num / den;
  }
}

// ---------------------------------------------------------------------------
// trend_norm: moving_avg(k=25, edge-replicated) -> LayerNorm(seasonal) + trend
// ---------------------------------------------------------------------------
__global__ __launch_bounds__(256)
void trend_norm(const float* __restrict__ y, const float* __restrict__ g,
                const float* __restrict__ be, float* __restrict__ outp) {
  const int t = blockIdx.x, b = blockIdx.y;
  const int tid = threadIdx.x;
  __shared__ float red[256];
  __shared__ float red2[256];
  float seas[2], trend[2];
  float lsum = 0.f, lsum2 = 0.f;
#pragma unroll
  for (int u = 0; u < 2; ++u) {
    int d = tid + u * 256;
    float tr = 0.f;
    for (int j = -12; j <= 12; ++j) {
      int tt = t + j;
      tt = tt < 0 ? 0 : (tt > 95 ? 95 : tt);
      tr += y[((size_t)(b * 96 + tt)) * 512 + d];
    }
    tr *= (1.f / 25.f);
    float x = y[((size_t)(b * 96 + t)) * 512 + d];
    float se = x - tr;
    seas[u] = se;
    trend[u] = tr;
    lsum += se;
    lsum2 += se * se;
  }
  red[tid] = lsum;
  red2[tid] = lsum2;
  __syncthreads();
  for (int off = 128; off > 0; off >>= 1) {
    if (tid < off) {
      red[tid] += red[tid + off];
      red2[tid] += red2[tid + off];
    }
    __syncthreads();
  }
  float mu = red[0] / 512.f;
  float var = red2[0] / 512.f - mu * mu;
  float rs = rsqrtf(var + 1e-5f);
#pragma unroll
  for (int u = 0; u < 2; ++u) {
    int d = tid + u * 256;
    outp[((size_t)(b * 96 + t)) * 512 + d] = (seas[u] - mu) * rs * g[d] + be[d] + trend[u];
  }
}

// ---------------------------------------------------------------------------
// Penalty: sum(diff(om, axis=seq)^2) and sum(th^2) over a fused proj buffer.
// ---------------------------------------------------------------------------
__global__ __launch_bounds__(256)
void penalty(const float* __restrict__ base, int R, int nb, float mult,
             float* __restrict__ pen) {
  const int tid = threadIdx.x;
  size_t gid = (size_t)blockIdx.x * 256 + tid;
  size_t total = (size_t)nb * R * 16;
  float omv = 0.f, thv = 0.f;
  if (gid < total) {
    int j = (int)(gid & 15);
    size_t row = gid >> 4;
    int s = (int)(row % R);
    const float* r0 = base + row * NF;
    float th = r0[528 + j];
    thv = th * th;
    if (s < R - 1) {
      float d = r0[NF + 512 + j] - r0[512 + j];
      omv = d * d;
    }
  }
  __shared__ float ro[256], rt[256];
  ro[tid] = omv;
  rt[tid] = thv;
  __syncthreads();
  for (int off = 128; off > 0; off >>= 1) {
    if (tid < off) {
      ro[tid] += ro[tid + off];
      rt[tid] += rt[tid + off];
    }
    __syncthreads();
  }
  if (tid == 0) {
    atomicAdd(pen + 0, mult * ro[0]);
    atomicAdd(pen + 1, mult * rt[0]);
  }
}

// ---------------------------------------------------------------------------
// Layer-1 attention, MFMA version. grid (48 ltiles of 64, 8h, 8b).
// Per block: Q rot built on the fly [64,128]; K=Kr1[bh][96,128]; V[96,64].
// Rowsums stay in registers (C-layout lane mapping == epilogue mapping).
// ---------------------------------------------------------------------------
__global__ __launch_bounds__(256)
void attn1_mfma(const float* __restrict__ QF1, const float* __restrict__ Kr1,
                const float* __restrict__ V1, float* __restrict__ attn1) {
  const int lt = blockIdx.x, h = blockIdx.y, b = blockIdx.z;
  const int l0 = lt * 64;
  const int tid = threadIdx.x;
  const int wv = tid >> 6, lane = tid & 63, quad = lane >> 4, col = lane & 15;

  __shared__ __align__(16) ushort Qs[64][136];
  __shared__ __align__(16) ushort Ks[96][136];
  __shared__ __align__(16) ushort Vt[64][104];  // [d][s]
  __shared__ __align__(16) ushort Ps[64][104];  // [l][s]
  __shared__ float2 trigq[64][2];

  if (tid < 128) {
    int l = tid >> 1, m = tid & 1;
    const float* row = QF1 + (size_t)(b * L_ + l0 + l) * NF;
    float om = row[512 + h * 2 + m];
    float th = row[528 + h * 2 + m];
    float qa = fmaf(om, (float)(l0 + l) * (1.f / (float)L_), th);
    trigq[l][m] = make_float2(cosf(qa), sinf(qa));
  }
  __syncthreads();
  // rotated Q -> bf16 LDS
  for (int idx = tid; idx < 64 * 128; idx += 256) {
    int l = idx >> 7, d = idx & 127;
    int m = d >> 6, r = d & 63, c = r >> 4, e = r & 15;
    const float* row = QF1 + (size_t)(b * L_ + l0 + l) * NF + h * 64;
    float qc = row[c * 16 + e];
    float qp = row[(c ^ 1) * 16 + e];
    float2 tg = trigq[l][m];
    float sgn = (c == 0 || c == 3) ? -1.f : 1.f;
    Qs[l][d] = f2bf(fmaf(qc, tg.x, sgn * qp * tg.y));
  }
  // K (prebuilt fp32) -> bf16 LDS
  const float* Krb = Kr1 + (size_t)(b * 8 + h) * 96 * 128;
  for (int idx = tid; idx < 96 * 64; idx += 256) {
    int s = idx >> 6, d2 = (idx & 63) * 2;
    float2 kk = *(const float2*)(Krb + (size_t)s * 128 + d2);
    ushort2 u;
    u.x = f2bf(kk.x);
    u.y = f2bf(kk.y);
    *(ushort2*)&Ks[s][d2] = u;
  }
  // V transposed -> bf16 LDS
  for (int idx = tid; idx < 96 * 64; idx += 256) {
    int s = idx >> 6, d = idx & 63;
    Vt[d][s] = f2bf(V1[(size_t)(b * 96 + s) * 512 + h * 64 + d]);
  }
  __syncthreads();

  // QK^T: wave wv owns l-rows wv*16..+15; 6 n-tiles over 96 s
  bf16x8 aq[4];
#pragma unroll
  for (int k = 0; k < 4; ++k)
    aq[k] = *(const bf16x8*)&Qs[wv * 16 + col][k * 32 + quad * 8];
  f32x4 sacc[6];
#pragma unroll
  for (int nt = 0; nt < 6; ++nt) {
    f32x4 z = {0.f, 0.f, 0.f, 0.f};
    sacc[nt] = z;
#pragma unroll
    for (int k = 0; k < 4; ++k) {
      bf16x8 bkf = *(const bf16x8*)&Ks[nt * 16 + col][k * 32 + quad * 8];
      sacc[nt] = mfma16(aq[k], bkf, sacc[nt]);
    }
  }
  // exp + register rowsums + P->LDS
  float rsum[4] = {0.f, 0.f, 0.f, 0.f};
#pragma unroll
  for (int nt = 0; nt < 6; ++nt) {
#pragma unroll
    for (int r = 0; r < 4; ++r) {
      float p = __expf(sacc[nt][r] * 0.0625f);
      Ps[wv * 16 + quad * 4 + r][nt * 16 + col] = f2bf(p);
      rsum[r] += p;
    }
  }
#pragma unroll
  for (int r = 0; r < 4; ++r) {
#pragma unroll
    for (int off = 1; off < 16; off <<= 1) rsum[r] += __shfl_xor(rsum[r], off);
  }
  __syncthreads();
  // PV: wave wv keeps l-rows wv*16..+15; 4 n-tiles over 64 d, K=96
  bf16x8 ap[3];
#pragma unroll
  for (int kt = 0; kt < 3; ++kt)
    ap[kt] = *(const bf16x8*)&Ps[wv * 16 + col][kt * 32 + quad * 8];
  f32x4 oacc[4];
#pragma unroll
  for (int nt = 0; nt < 4; ++nt) {
    f32x4 z = {0.f, 0.f, 0.f, 0.f};
    oacc[nt] = z;
#pragma unroll
    for (int kt = 0; kt < 3; ++kt) {
      bf16x8 bvf = *(const bf16x8*)&Vt[nt * 16 + col][kt * 32 + quad * 8];
      oacc[nt] = mfma16(ap[kt], bvf, oacc[nt]);
    }
  }
  float inv[4];
#pragma unroll
  for (int r = 0; r < 4; ++r) inv[r] = 1.f / rsum[r];
#pragma unroll
  for (int nt = 0; nt < 4; ++nt) {
#pragma unroll
    for (int r = 0; r < 4; ++r) {
      int l = wv * 16 + quad * 4 + r;
      attn1[(size_t)(b * L_ + l0 + l) * 512 + h * 64 + nt * 16 + col] =
          oacc[nt][r] * inv[r];
    }
  }
}

// ---------------------------------------------------------------------------
extern "C" void kernel_launch(void* const* d_in, const int* in_sizes, int n_in,
                              void* d_out, int out_size, void* d_ws, size_t ws_size,
                              hipStream_t stream) {
  (void)in_sizes; (void)n_in; (void)out_size; (void)ws_size;
  const float* queries = (const float*)d_in[0];
  const float* keys = (const float*)d_in[1];
  const float* values = (const float*)d_in[2];
  const float* Wq = (const float*)d_in[3];
  const float* bq = (const float*)d_in[4];
  const float* Wk = (const float*)d_in[5];
  const float* bk = (const float*)d_in[6];
  const float* Wv = (const float*)d_in[7];
  const float* bv = (const float*)d_in[8];
  const float* Wqo = (const float*)d_in[9];
  const float* bqo = (const float*)d_in[10];
  const float* Wko = (const float*)d_in[11];
  const float* bko = (const float*)d_in[12];
  const float* Wqt = (const float*)d_in[13];
  const float* bqt = (const float*)d_in[14];
  const float* Wkt = (const float*)d_in[15];
  const float* bkt = (const float*)d_in[16];
  const float* Wo = (const float*)d_in[17];
  const float* bo = (const float*)d_in[18];
  const float* I = (const float*)d_in[19];
  const float* ln_g = (const float*)d_in[20];
  const float* ln_b = (const float*)d_in[21];
  float* out = (float*)d_out;

  float* ws = (float*)d_ws;
  size_t off = 0;
  auto alloc = [&](size_t n) {
    float* p = ws + off;
    off += (n + 3) & ~(size_t)3;
    return p;
  };
  float* WCAT0K = alloc(512 * 544);
  float* WCAT0Q = alloc(512 * 544);
  float* WCAT1K = alloc(512 * 544);
  float* WCAT1Q = alloc(512 * 544);
  float* BCAT0K = alloc(544);
  float* BCAT0Q = alloc(544);
  float* BCAT1K = alloc(544);
  float* BCAT1Q = alloc(544);
  float* pen = alloc(16);
  float* QF0 = alloc(96 * 544);
  float* Qr0 = alloc(8 * 96 * 128);
  float* KF0 = alloc((size_t)24576 * 544);  // reused as QF1 after attention-0
  float* V0 = alloc((size_t)24576 * 512);   // reused as attn1 output
  float* attn0 = alloc(768 * 512);
  float* y0 = alloc(768 * 512);
  float* xind = alloc(768 * 512);
  float* KF1 = alloc(768 * 544);
  float* V1 = alloc(768 * 512);
  float* Kr1 = alloc((size_t)64 * 96 * 128);
  float* accP = alloc((size_t)64 * NSC * 96 * 64);
  float* sumP = alloc((size_t)64 * NSC * 96);
  float* QF1 = KF0;
  float* attn1 = V0;

  init_pen<<<1, 64, 0, stream>>>(pen);
  const int packBlocks = (512 * 544 + 255) / 256;
  pack_w<<<packBlocks, 256, 0, stream>>>(Wk, Wko, Wkt, bk, bko, bkt, WCAT0K, BCAT0K);
  pack_w<<<packBlocks, 256, 0, stream>>>(Wq, Wqo, Wqt, bq, bqo, bqt, WCAT0Q, BCAT0Q);
  pack_w<<<packBlocks, 256, 0, stream>>>(Wk + 262144, Wko + 8192, Wkt + 8192,
                                         bk + 512, bko + 16, bkt + 16, WCAT1K, BCAT1K);
  pack_w<<<packBlocks, 256, 0, stream>>>(Wq + 262144, Wqo + 8192, Wqt + 8192,
                                         bq + 512, bqo + 16, bqt + 16, WCAT1Q, BCAT1Q);

  // ---- layer 0 ----
  gemm_k512<<<dim3(9, 384), 256, 0, stream>>>(keys, WCAT0K, BCAT0K, KF0, 24576, 544, 1);
  gemm_k512<<<dim3(8, 384), 256, 0, stream>>>(values, Wv, bv, V0, 24576, 512, 0);
  gemm_k512<<<dim3(9, 2), 256, 0, stream>>>(I, WCAT0Q, BCAT0Q, QF0, 96, 544, 1);
  build_qr0<<<96, 256, 0, stream>>>(QF0, Qr0);
  penalty<<<(96 * 16 + 255) / 256, 256, 0, stream>>>(QF0, 96, 1, 8.f, pen);
  penalty<<<(24576 * 16 + 255) / 256, 256, 0, stream>>>(KF0, 3072, 8, 1.f, pen);
  attn0_mfma<<<dim3(8, 8, 8), 256, 0, stream>>>(KF0, V0, Qr0, accP, sumP);
  attn0_stage2<<<dim3(96, 8), 256, 0, stream>>>(accP, sumP, attn0);
  gemm_k512<<<dim3(8, 12), 256, 0, stream>>>(attn0, Wo, bo, y0, 768, 512, 0);
  trend_norm<<<dim3(96, 8), 256, 0, stream>>>(y0, ln_g, ln_b, xind);

  // ---- layer 1 ----
  gemm_k512<<<dim3(9, 12), 256, 0, stream>>>(xind, WCAT1K, BCAT1K, KF1, 768, 544, 1);
  gemm_k512<<<dim3(8, 12), 256, 0, stream>>>(xind, Wv + 262144, bv + 512, V1, 768, 512, 0);
  build_kr1<<<768, 256, 0, stream>>>(KF1, Kr1);
  penalty<<<(768 * 16 + 255) / 256, 256, 0, stream>>>(KF1, 96, 8, 1.f, pen);
  gemm_k512<<<dim3(9, 384), 256, 0, stream>>>(queries, WCAT1Q, BCAT1Q, QF1, 24576, 544, 1);
  penalty<<<(24576 * 16 + 255) / 256, 256, 0, stream>>>(QF1, 3072, 8, 1.f, pen);
  attn1_mfma<<<dim3(48, 8, 8), 256, 0, stream>>>(QF1, Kr1, V1, attn1);
  gemm_k512<<<dim3(8, 384), 256, 0, stream>>>(attn1, Wo + 262144, bo + 512, out, 24576, 512, 0);
  write_pen<<<1, 64, 0, stream>>>(pen, out);
}

// Round 3
// 783.593 us; speedup vs baseline: 3.8024x; 1.7441x over previous
//
#include <hip/hip_runtime.h>
#include <math.h>

#define PI_F 3.14159265358979323846f

namespace {
constexpr int B_ = 8;
constexpr int L_ = 3072;
constexpr int S_ = 3072;
constexpr int H_ = 8;
constexpr int NF = 544;          // fused projection width: 512 (main) + 16 (omega) + 16 (theta)
constexpr int NSC = 8;           // s-chunks for layer-0 attention
constexpr int SCHUNK = S_ / NSC; // 384
}

typedef __attribute__((ext_vector_type(8))) short bf16x8;
typedef __attribute__((ext_vector_type(4))) float f32x4;

__device__ inline f32x4 mfma16(bf16x8 a, bf16x8 b, f32x4 c) {
  return __builtin_amdgcn_mfma_f32_16x16x32_bf16(a, b, c, 0, 0, 0);
}

__device__ inline ushort f2bf(float f) {
  union { float f; unsigned u; } v;
  v.f = f;
  unsigned r = v.u + 0x7FFFu + ((v.u >> 16) & 1u);
  return (ushort)(r >> 16);
}

// async global->LDS, 16B per lane; lds base must be wave-uniform.
__device__ inline void gl_lds16(const void* g, void* l) {
  __builtin_amdgcn_global_load_lds(
      (const __attribute__((address_space(1))) unsigned int*)g,
      (__attribute__((address_space(3))) unsigned int*)l, 16, 0, 0);
}

// ---------------------------------------------------------------------------
// misc small kernels
// ---------------------------------------------------------------------------
__global__ void init_pen(float* pen) {
  if (threadIdx.x < 16) pen[threadIdx.x] = 0.f;
}

__global__ void write_pen(const float* __restrict__ pen, float* __restrict__ out) {
  if (threadIdx.x == 0) out[12582912] = pen[0];
  if (threadIdx.x == 1) out[12582913] = pen[1];
}

// Pack Wmain[512,512] | Wom[512,16] | Wth[512,16] -> Wcat[512,544] fp32 (+bias)
__global__ void pack_w(const float* __restrict__ Wm, const float* __restrict__ Wo_,
                       const float* __restrict__ Wt, const float* __restrict__ bm,
                       const float* __restrict__ bo_, const float* __restrict__ bt,
                       float* __restrict__ Wcat, float* __restrict__ bcat) {
  int gid = blockIdx.x * 256 + threadIdx.x;
  if (gid < 512 * 544) {
    int k = gid / 544, n = gid % 544;
    float v;
    if (n < 512) v = Wm[(size_t)k * 512 + n];
    else if (n < 528) v = Wo_[k * 16 + (n - 512)];
    else v = Wt[k * 16 + (n - 528)];
    Wcat[gid] = v;
  }
  if (gid < 544) {
    float v;
    if (gid < 512) v = bm[gid];
    else if (gid < 528) v = bo_[gid - 512];
    else v = bt[gid - 528];
    bcat[gid] = v;
  }
}

// Transposed bf16 weight pack: BT[640][512], rows 544..639 zeroed; bias[544].
__global__ void pack_wt_fused(const float* __restrict__ Wm, const float* __restrict__ Wo_,
                              const float* __restrict__ Wt, const float* __restrict__ bm,
                              const float* __restrict__ bo_, const float* __restrict__ bt,
                              ushort* __restrict__ BT, float* __restrict__ bias) {
  int gid = blockIdx.x * 256 + threadIdx.x;
  if (gid < 640 * 512) {
    int n = gid >> 9, k = gid & 511;
    float v = 0.f;
    if (n < 512) v = Wm[(size_t)k * 512 + n];
    else if (n < 528) v = Wo_[k * 16 + (n - 512)];
    else if (n < 544) v = Wt[k * 16 + (n - 528)];
    BT[gid] = f2bf(v);
  }
  if (gid < 544)
    bias[gid] = (gid < 512) ? bm[gid] : (gid < 528 ? bo_[gid - 512] : bt[gid - 528]);
}

// Transposed bf16 weight pack, plain 512x512 + bias[512].
__global__ void pack_wt_plain(const float* __restrict__ W, const float* __restrict__ b,
                              ushort* __restrict__ BT, float* __restrict__ bias) {
  int gid = blockIdx.x * 256 + threadIdx.x;
  if (gid < 512 * 512) {
    int n = gid >> 9, k = gid & 511;
    BT[gid] = f2bf(W[(size_t)k * 512 + n]);
  }
  if (gid < 512) bias[gid] = b[gid];
}

// fp32 -> bf16 cast, 8 elems/thread
__global__ __launch_bounds__(256)
void cast_bf16(const float* __restrict__ src, ushort* __restrict__ dst, int n8) {
  int gid = blockIdx.x * 256 + threadIdx.x;
  if (gid < n8) {
    float4 a = ((const float4*)src)[(size_t)gid * 2];
    float4 b = ((const float4*)src)[(size_t)gid * 2 + 1];
    ushort u[8] = {f2bf(a.x), f2bf(a.y), f2bf(a.z), f2bf(a.w),
                   f2bf(b.x), f2bf(b.y), f2bf(b.z), f2bf(b.w)};
    ((uint4*)dst)[gid] = *(uint4*)u;
  }
}

// ---------------------------------------------------------------------------
// bf16 MFMA GEMM: C[M,Nout] = act(A[M,512]bf16 @ BT[Npad,512]bf16^T + bias)
// 128x128 tile, BK=32, 4 waves (2x2), global_load_lds width-16 staging.
// M must be a multiple of 128 (grid.y = M/128).
// ---------------------------------------------------------------------------
__global__ __launch_bounds__(256)
void gemm_bf16_mfma(const ushort* __restrict__ A, const ushort* __restrict__ BT,
                    const float* __restrict__ bias, float* __restrict__ C,
                    int ldc, int Nout, int act) {
  __shared__ ushort As[128][32];
  __shared__ ushort Bs[128][32];
  const int tid = threadIdx.x;
  const int wv = tid >> 6, lane = tid & 63, quad = lane >> 4, col = lane & 15;
  const int wm = wv & 1, wn = wv >> 1;
  const int m0 = blockIdx.y * 128, n0 = blockIdx.x * 128;

  const int srow = lane >> 2;        // 0..15 row within 16-row staging group
  const int scol = (lane & 3) * 8;   // ushort offset (16B granules)

  f32x4 acc[4][4];
#pragma unroll
  for (int i = 0; i < 4; ++i)
#pragma unroll
    for (int j = 0; j < 4; ++j) {
      f32x4 z = {0.f, 0.f, 0.f, 0.f};
      acc[i][j] = z;
    }

  const ushort* Ag = A + (size_t)(m0 + wv * 32) * 512;
  const ushort* Bg = BT + (size_t)(n0 + wv * 32) * 512;

  for (int k0 = 0; k0 < 512; k0 += 32) {
    __syncthreads();
    gl_lds16(Ag + (size_t)srow * 512 + k0 + scol, &As[wv * 32][0]);
    gl_lds16(Ag + (size_t)(srow + 16) * 512 + k0 + scol, &As[wv * 32 + 16][0]);
    gl_lds16(Bg + (size_t)srow * 512 + k0 + scol, &Bs[wv * 32][0]);
    gl_lds16(Bg + (size_t)(srow + 16) * 512 + k0 + scol, &Bs[wv * 32 + 16][0]);
    __syncthreads();
    bf16x8 av[4], bv[4];
#pragma unroll
    for (int mi = 0; mi < 4; ++mi)
      av[mi] = *(const bf16x8*)&As[wm * 64 + mi * 16 + col][quad * 8];
#pragma unroll
    for (int ni = 0; ni < 4; ++ni)
      bv[ni] = *(const bf16x8*)&Bs[wn * 64 + ni * 16 + col][quad * 8];
#pragma unroll
    for (int mi = 0; mi < 4; ++mi)
#pragma unroll
      for (int ni = 0; ni < 4; ++ni)
        acc[mi][ni] = mfma16(av[mi], bv[ni], acc[mi][ni]);
  }

#pragma unroll
  for (int mi = 0; mi < 4; ++mi) {
#pragma unroll
    for (int ni = 0; ni < 4; ++ni) {
      int n = n0 + wn * 64 + ni * 16 + col;
      if (n >= Nout) continue;
      float bs = bias[n];
#pragma unroll
      for (int r = 0; r < 4; ++r) {
        int m = m0 + wm * 64 + mi * 16 + quad * 4 + r;
        float v = acc[mi][ni][r] + bs;
        if (act && n >= 512) v = (n < 528) ? fmaxf(v, 0.f) : tanhf(v) * PI_F;
        C[(size_t)m * ldc + n] = v;
      }
    }
  }
}

// ---------------------------------------------------------------------------
// Generic K=512 fp32 GEMM (kept for small-M dispatches).
// ---------------------------------------------------------------------------
__global__ __launch_bounds__(256)
void gemm_k512(const float* __restrict__ A, const float* __restrict__ W,
               const float* __restrict__ bias, float* __restrict__ C,
               int M, int N, int act) {
  __shared__ float As[16][68];
  __shared__ float Ws_[16][68];
  const int tid = threadIdx.x;
  const int tx = tid & 15, ty = tid >> 4;
  const int m0 = blockIdx.y * 64, n0 = blockIdx.x * 64;

  float acc[4][4];
#pragma unroll
  for (int i = 0; i < 4; ++i)
#pragma unroll
    for (int j = 0; j < 4; ++j) acc[i][j] = 0.f;

  const int arow = tid >> 2;
  const int acol4 = (tid & 3) * 4;
  const int wrow = tid >> 4;
  const int wcol4 = (tid & 15) * 4;

  for (int k0 = 0; k0 < 512; k0 += 16) {
    float4 av = make_float4(0.f, 0.f, 0.f, 0.f);
    int gm = m0 + arow;
    if (gm < M) av = *(const float4*)(A + (size_t)gm * 512 + k0 + acol4);
    As[acol4 + 0][arow] = av.x;
    As[acol4 + 1][arow] = av.y;
    As[acol4 + 2][arow] = av.z;
    As[acol4 + 3][arow] = av.w;
    float4 wv;
    int gn = n0 + wcol4;
    if (gn + 3 < N) {
      wv = *(const float4*)(W + (size_t)(k0 + wrow) * N + gn);
    } else {
      float tmp[4] = {0.f, 0.f, 0.f, 0.f};
      for (int u = 0; u < 4; ++u)
        if (gn + u < N) tmp[u] = W[(size_t)(k0 + wrow) * N + gn + u];
      wv = make_float4(tmp[0], tmp[1], tmp[2], tmp[3]);
    }
    *(float4*)&Ws_[wrow][wcol4] = wv;
    __syncthreads();
#pragma unroll
    for (int k = 0; k < 16; ++k) {
      float4 a4 = *(const float4*)&As[k][ty * 4];
      float4 b4 = *(const float4*)&Ws_[k][tx * 4];
      float a[4] = {a4.x, a4.y, a4.z, a4.w};
      float b[4] = {b4.x, b4.y, b4.z, b4.w};
#pragma unroll
      for (int i = 0; i < 4; ++i)
#pragma unroll
        for (int j = 0; j < 4; ++j) acc[i][j] = fmaf(a[i], b[j], acc[i][j]);
    }
    __syncthreads();
  }

#pragma unroll
  for (int i = 0; i < 4; ++i) {
    int gm = m0 + ty * 4 + i;
    if (gm >= M) continue;
#pragma unroll
    for (int j = 0; j < 4; ++j) {
      int gn = n0 + tx * 4 + j;
      if (gn >= N) continue;
      float v = acc[i][j] + bias[gn];
      if (act && gn >= 512) v = (gn < 528) ? fmaxf(v, 0.f) : tanhf(v) * PI_F;
      C[(size_t)gm * N + gn] = v;
    }
  }
}

// ---------------------------------------------------------------------------
// Build Qr0 [8h][96l][128d] from QF0 [96][544] (layer-0 q-side, no batch).
// ---------------------------------------------------------------------------
__global__ __launch_bounds__(256)
void build_qr0(const float* __restrict__ QF0, float* __restrict__ Qr0) {
  const int l = blockIdx.x;
  const float* row = QF0 + (size_t)l * NF;
  __shared__ float2 trig[8][2];
  const int tid = threadIdx.x;
  if (tid < 16) {
    int h = tid >> 1, m = tid & 1;
    float om = row[512 + h * 2 + m], th = row[528 + h * 2 + m];
    float qa = fmaf(om, (float)l / 96.f, th);
    trig[h][m] = make_float2(cosf(qa), sinf(qa));
  }
  __syncthreads();
  for (int idx = tid; idx < 1024; idx += 256) {
    int h = idx >> 7, d = idx & 127;
    int m = d >> 6, r = d & 63, c = r >> 4, e = r & 15;
    float qc = row[h * 64 + c * 16 + e];
    float qp = row[h * 64 + (c ^ 1) * 16 + e];
    float2 tg = trig[h][m];
    float sgn = (c == 0 || c == 3) ? -1.f : 1.f;
    Qr0[((size_t)h * 96 + l) * 128 + d] = fmaf(qc, tg.x, sgn * qp * tg.y);
  }
}

// ---------------------------------------------------------------------------
// Build Kr1 [b*8+h][96s][128d] from KF1 [768][544] (layer-1 k-side).
// ---------------------------------------------------------------------------
__global__ __launch_bounds__(256)
void build_kr1(const float* __restrict__ KF1, float* __restrict__ Kr1) {
  const int rs = blockIdx.x;
  const int b = rs / 96, s = rs % 96;
  const float* row = KF1 + (size_t)rs * NF;
  __shared__ float2 trig[8][2];
  const int tid = threadIdx.x;
  if (tid < 16) {
    int h = tid >> 1, m = tid & 1;
    float om = row[512 + h * 2 + m], th = row[528 + h * 2 + m];
    float ka = fmaf(om, (float)s / 96.f, th);
    trig[h][m] = make_float2(cosf(ka), sinf(ka));
  }
  __syncthreads();
  for (int idx = tid; idx < 1024; idx += 256) {
    int h = idx >> 7, d = idx & 127;
    int m = d >> 6, r = d & 63, c = r >> 4, e = r & 15;
    float kc = row[h * 64 + c * 16 + e];
    float kp = row[h * 64 + (c ^ 2) * 16 + e];
    float2 tg = trig[h][m];
    float sgn = (c < 2) ? -1.f : 1.f;
    Kr1[(((size_t)(b * 8 + h)) * 96 + s) * 128 + d] = fmaf(kc, tg.x, sgn * kp * tg.y);
  }
}

// ---------------------------------------------------------------------------
// Layer-0 attention, MFMA. grid (8 sc, 8 h, 8 b), 256 threads.
// ---------------------------------------------------------------------------
__global__ __launch_bounds__(256)
void attn0_mfma(const float* __restrict__ KF0, const float* __restrict__ V0,
                const float* __restrict__ Qr0, float* __restrict__ accP,
                float* __restrict__ sumP) {
  const int sc = blockIdx.x, h = blockIdx.y, b = blockIdx.z;
  const int tid = threadIdx.x;
  const int wv = tid >> 6, lane = tid & 63, quad = lane >> 4, col = lane & 15;

  __shared__ __align__(16) ushort Qs[96][136];
  __shared__ __align__(16) ushort Ks[64][136];
  __shared__ __align__(16) ushort Vt[64][72];
  __shared__ __align__(16) ushort Ps[96][72];
  __shared__ float rowsum[96];
  __shared__ float2 trig[64][2];

  const float* Qh = Qr0 + ((size_t)h * 96) * 128;
  for (int idx = tid; idx < 96 * 64; idx += 256) {
    int l = idx >> 6, d2 = (idx & 63) * 2;
    float2 q = *(const float2*)(Qh + (size_t)l * 128 + d2);
    ushort2 u;
    u.x = f2bf(q.x);
    u.y = f2bf(q.y);
    *(ushort2*)&Qs[l][d2] = u;
  }
  if (tid < 96) rowsum[tid] = 0.f;

  f32x4 oacc[6];
#pragma unroll
  for (int i = 0; i < 6; ++i) {
    f32x4 z = {0.f, 0.f, 0.f, 0.f};
    oacc[i] = z;
  }

  const int s0g = sc * SCHUNK;
  for (int t = 0; t < 6; ++t) {
    const int sb = s0g + t * 64;
    __syncthreads();
    if (tid < 128) {
      int s = tid >> 1, m = tid & 1;
      const float* row = KF0 + (size_t)(b * S_ + sb + s) * NF;
      float om = row[512 + h * 2 + m];
      float th = row[528 + h * 2 + m];
      float ka = fmaf(om, (float)(sb + s) * (1.f / (float)S_), th);
      trig[s][m] = make_float2(cosf(ka), sinf(ka));
    }
    __syncthreads();
    for (int idx = tid; idx < 64 * 128; idx += 256) {
      int s = idx >> 7, d = idx & 127;
      int m = d >> 6, r = d & 63, c = r >> 4, e = r & 15;
      const float* row = KF0 + (size_t)(b * S_ + sb + s) * NF + h * 64;
      float kc = row[c * 16 + e];
      float kp = row[(c ^ 2) * 16 + e];
      float2 tg = trig[s][m];
      float sgn = (c < 2) ? -1.f : 1.f;
      Ks[s][d] = f2bf(fmaf(kc, tg.x, sgn * kp * tg.y));
    }
    for (int idx = tid; idx < 64 * 64; idx += 256) {
      int s = idx >> 6, d = idx & 63;
      Vt[d][s] = f2bf(V0[(size_t)(b * S_ + sb + s) * 512 + h * 64 + d]);
    }
    __syncthreads();
    bf16x8 bk[4];
#pragma unroll
    for (int k = 0; k < 4; ++k)
      bk[k] = *(const bf16x8*)&Ks[wv * 16 + col][k * 32 + quad * 8];
    f32x4 sacc[6];
#pragma unroll
    for (int mt = 0; mt < 6; ++mt) {
      f32x4 z = {0.f, 0.f, 0.f, 0.f};
      sacc[mt] = z;
#pragma unroll
      for (int k = 0; k < 4; ++k) {
        bf16x8 a = *(const bf16x8*)&Qs[mt * 16 + col][k * 32 + quad * 8];
        sacc[mt] = mfma16(a, bk[k], sacc[mt]);
      }
    }
#pragma unroll
    for (int mt = 0; mt < 6; ++mt) {
      float pr[4];
#pragma unroll
      for (int r = 0; r < 4; ++r) {
        float p = __expf(sacc[mt][r] * 0.0625f);
        pr[r] = p;
        Ps[mt * 16 + quad * 4 + r][wv * 16 + col] = f2bf(p);
      }
#pragma unroll
      for (int r = 0; r < 4; ++r) {
#pragma unroll
        for (int off = 1; off < 16; off <<= 1) pr[r] += __shfl_xor(pr[r], off);
      }
      if (col == 0) {
#pragma unroll
        for (int r = 0; r < 4; ++r)
          atomicAdd(&rowsum[mt * 16 + quad * 4 + r], pr[r]);
      }
    }
    __syncthreads();
    bf16x8 bv0 = *(const bf16x8*)&Vt[wv * 16 + col][quad * 8];
    bf16x8 bv1 = *(const bf16x8*)&Vt[wv * 16 + col][32 + quad * 8];
#pragma unroll
    for (int mt = 0; mt < 6; ++mt) {
      bf16x8 a0 = *(const bf16x8*)&Ps[mt * 16 + col][quad * 8];
      oacc[mt] = mfma16(a0, bv0, oacc[mt]);
      bf16x8 a1 = *(const bf16x8*)&Ps[mt * 16 + col][32 + quad * 8];
      oacc[mt] = mfma16(a1, bv1, oacc[mt]);
    }
  }
  __syncthreads();
  const size_t pbase = (((size_t)(b * 8 + h)) * NSC + sc) * 96;
#pragma unroll
  for (int mt = 0; mt < 6; ++mt) {
#pragma unroll
    for (int r = 0; r < 4; ++r) {
      int l = mt * 16 + quad * 4 + r;
      accP[(pbase + l) * 64 + wv * 16 + col] = oacc[mt][r];
    }
  }
  if (tid < 96) sumP[pbase + tid] = rowsum[tid];
}

// Stage 2: combine the NSC chunk partials -> attn0 [b*96+l][h*64+d]
__global__ __launch_bounds__(256)
void attn0_stage2(const float* __restrict__ accP, const float* __restrict__ sumP,
                  float* __restrict__ attn0) {
  const int l = blockIdx.x, b = blockIdx.y;
  const int tid = threadIdx.x;
  for (int e = tid; e < 512; e += 256) {
    int h = e >> 6, d = e & 63;
    size_t base = ((size_t)(b * 8 + h)) * NSC * 96;
    float num = 0.f, den = 0.f;
    for (int scv = 0; scv < NSC; ++scv) {
      size_t pb = base + (size_t)scv * 96 + l;
      num += accP[pb * 64 + d];
      den += sumP[pb];
    }
    attn0[((size_t)(b * 96 + l)) * 512 + e] = num / den;
  }
}

// ---------------------------------------------------------------------------
// trend_norm: moving_avg(k=25, edge-replicated) -> LayerNorm(seasonal) + trend
// ---------------------------------------------------------------------------
__global__ __launch_bounds__(256)
void trend_norm(const float* __restrict__ y, const float* __restrict__ g,
                const float* __restrict__ be, float* __restrict__ outp) {
  const int t = blockIdx.x, b = blockIdx.y;
  const int tid = threadIdx.x;
  __shared__ float red[256];
  __shared__ float red2[256];
  float seas[2], trend[2];
  float lsum = 0.f, lsum2 = 0.f;
#pragma unroll
  for (int u = 0; u < 2; ++u) {
    int d = tid + u * 256;
    float tr = 0.f;
    for (int j = -12; j <= 12; ++j) {
      int tt = t + j;
      tt = tt < 0 ? 0 : (tt > 95 ? 95 : tt);
      tr += y[((size_t)(b * 96 + tt)) * 512 + d];
    }
    tr *= (1.f / 25.f);
    float x = y[((size_t)(b * 96 + t)) * 512 + d];
    float se = x - tr;
    seas[u] = se;
    trend[u] = tr;
    lsum += se;
    lsum2 += se * se;
  }
  red[tid] = lsum;
  red2[tid] = lsum2;
  __syncthreads();
  for (int off = 128; off > 0; off >>= 1) {
    if (tid < off) {
      red[tid] += red[tid + off];
      red2[tid] += red2[tid + off];
    }
    __syncthreads();
  }
  float mu = red[0] / 512.f;
  float var = red2[0] / 512.f - mu * mu;
  float rs = rsqrtf(var + 1e-5f);
#pragma unroll
  for (int u = 0; u < 2; ++u) {
    int d = tid + u * 256;
    outp[((size_t)(b * 96 + t)) * 512 + d] = (seas[u] - mu) * rs * g[d] + be[d] + trend[u];
  }
}

// ---------------------------------------------------------------------------
// Penalty: sum(diff(om, axis=seq)^2) and sum(th^2) over a fused proj buffer.
// ---------------------------------------------------------------------------
__global__ __launch_bounds__(256)
void penalty(const float* __restrict__ base, int R, int nb, float mult,
             float* __restrict__ pen) {
  const int tid = threadIdx.x;
  size_t gid = (size_t)blockIdx.x * 256 + tid;
  size_t total = (size_t)nb * R * 16;
  float omv = 0.f, thv = 0.f;
  if (gid < total) {
    int j = (int)(gid & 15);
    size_t row = gid >> 4;
    int s = (int)(row % R);
    const float* r0 = base + row * NF;
    float th = r0[528 + j];
    thv = th * th;
    if (s < R - 1) {
      float d = r0[NF + 512 + j] - r0[512 + j];
      omv = d * d;
    }
  }
  __shared__ float ro[256], rt[256];
  ro[tid] = omv;
  rt[tid] = thv;
  __syncthreads();
  for (int off = 128; off > 0; off >>= 1) {
    if (tid < off) {
      ro[tid] += ro[tid + off];
      rt[tid] += rt[tid + off];
    }
    __syncthreads();
  }
  if (tid == 0) {
    atomicAdd(pen + 0, mult * ro[0]);
    atomicAdd(pen + 1, mult * rt[0]);
  }
}

// ---------------------------------------------------------------------------
// Layer-1 attention, MFMA. grid (48 ltiles of 64, 8h, 8b). bf16 output.
// ---------------------------------------------------------------------------
__global__ __launch_bounds__(256)
void attn1_mfma(const float* __restrict__ QF1, const float* __restrict__ Kr1,
                const float* __restrict__ V1, ushort* __restrict__ attn1) {
  const int lt = blockIdx.x, h = blockIdx.y, b = blockIdx.z;
  const int l0 = lt * 64;
  const int tid = threadIdx.x;
  const int wv = tid >> 6, lane = tid & 63, quad = lane >> 4, col = lane & 15;

  __shared__ __align__(16) ushort Qs[64][136];
  __shared__ __align__(16) ushort Ks[96][136];
  __shared__ __align__(16) ushort Vt[64][104];
  __shared__ __align__(16) ushort Ps[64][104];
  __shared__ float2 trigq[64][2];

  if (tid < 128) {
    int l = tid >> 1, m = tid & 1;
    const float* row = QF1 + (size_t)(b * L_ + l0 + l) * NF;
    float om = row[512 + h * 2 + m];
    float th = row[528 + h * 2 + m];
    float qa = fmaf(om, (float)(l0 + l) * (1.f / (float)L_), th);
    trigq[l][m] = make_float2(cosf(qa), sinf(qa));
  }
  __syncthreads();
  for (int idx = tid; idx < 64 * 128; idx += 256) {
    int l = idx >> 7, d = idx & 127;
    int m = d >> 6, r = d & 63, c = r >> 4, e = r & 15;
    const float* row = QF1 + (size_t)(b * L_ + l0 + l) * NF + h * 64;
    float qc = row[c * 16 + e];
    float qp = row[(c ^ 1) * 16 + e];
    float2 tg = trigq[l][m];
    float sgn = (c == 0 || c == 3) ? -1.f : 1.f;
    Qs[l][d] = f2bf(fmaf(qc, tg.x, sgn * qp * tg.y));
  }
  const float* Krb = Kr1 + (size_t)(b * 8 + h) * 96 * 128;
  for (int idx = tid; idx < 96 * 64; idx += 256) {
    int s = idx >> 6, d2 = (idx & 63) * 2;
    float2 kk = *(const float2*)(Krb + (size_t)s * 128 + d2);
    ushort2 u;
    u.x = f2bf(kk.x);
    u.y = f2bf(kk.y);
    *(ushort2*)&Ks[s][d2] = u;
  }
  for (int idx = tid; idx < 96 * 64; idx += 256) {
    int s = idx >> 6, d = idx & 63;
    Vt[d][s] = f2bf(V1[(size_t)(b * 96 + s) * 512 + h * 64 + d]);
  }
  __syncthreads();

  bf16x8 aq[4];
#pragma unroll
  for (int k = 0; k < 4; ++k)
    aq[k] = *(const bf16x8*)&Qs[wv * 16 + col][k * 32 + quad * 8];
  f32x4 sacc[6];
#pragma unroll
  for (int nt = 0; nt < 6; ++nt) {
    f32x4 z = {0.f, 0.f, 0.f, 0.f};
    sacc[nt] = z;
#pragma unroll
    for (int k = 0; k < 4; ++k) {
      bf16x8 bkf = *(const bf16x8*)&Ks[nt * 16 + col][k * 32 + quad * 8];
      sacc[nt] = mfma16(aq[k], bkf, sacc[nt]);
    }
  }
  float rsum[4] = {0.f, 0.f, 0.f, 0.f};
#pragma unroll
  for (int nt = 0; nt < 6; ++nt) {
#pragma unroll
    for (int r = 0; r < 4; ++r) {
      float p = __expf(sacc[nt][r] * 0.0625f);
      Ps[wv * 16 + quad * 4 + r][nt * 16 + col] = f2bf(p);
      rsum[r] += p;
    }
  }
#pragma unroll
  for (int r = 0; r < 4; ++r) {
#pragma unroll
    for (int off = 1; off < 16; off <<= 1) rsum[r] += __shfl_xor(rsum[r], off);
  }
  __syncthreads();
  bf16x8 ap[3];
#pragma unroll
  for (int kt = 0; kt < 3; ++kt)
    ap[kt] = *(const bf16x8*)&Ps[wv * 16 + col][kt * 32 + quad * 8];
  f32x4 oacc[4];
#pragma unroll
  for (int nt = 0; nt < 4; ++nt) {
    f32x4 z = {0.f, 0.f, 0.f, 0.f};
    oacc[nt] = z;
#pragma unroll
    for (int kt = 0; kt < 3; ++kt) {
      bf16x8 bvf = *(const bf16x8*)&Vt[nt * 16 + col][kt * 32 + quad * 8];
      oacc[nt] = mfma16(ap[kt], bvf, oacc[nt]);
    }
  }
  float inv[4];
#pragma unroll
  for (int r = 0; r < 4; ++r) inv[r] = 1.f / rsum[r];
#pragma unroll
  for (int nt = 0; nt < 4; ++nt) {
#pragma unroll
    for (int r = 0; r < 4; ++r) {
      int l = wv * 16 + quad * 4 + r;
      attn1[(size_t)(b * L_ + l0 + l) * 512 + h * 64 + nt * 16 + col] =
          f2bf(oacc[nt][r] * inv[r]);
    }
  }
}

// ---------------------------------------------------------------------------
extern "C" void kernel_launch(void* const* d_in, const int* in_sizes, int n_in,
                              void* d_out, int out_size, void* d_ws, size_t ws_size,
                              hipStream_t stream) {
  (void)in_sizes; (void)n_in; (void)out_size; (void)ws_size;
  const float* queries = (const float*)d_in[0];
  const float* keys = (const float*)d_in[1];
  const float* values = (const float*)d_in[2];
  const float* Wq = (const float*)d_in[3];
  const float* bq = (const float*)d_in[4];
  const float* Wk = (const float*)d_in[5];
  const float* bk = (const float*)d_in[6];
  const float* Wv = (const float*)d_in[7];
  const float* bv = (const float*)d_in[8];
  const float* Wqo = (const float*)d_in[9];
  const float* bqo = (const float*)d_in[10];
  const float* Wko = (const float*)d_in[11];
  const float* bko = (const float*)d_in[12];
  const float* Wqt = (const float*)d_in[13];
  const float* bqt = (const float*)d_in[14];
  const float* Wkt = (const float*)d_in[15];
  const float* bkt = (const float*)d_in[16];
  const float* Wo = (const float*)d_in[17];
  const float* bo = (const float*)d_in[18];
  const float* I = (const float*)d_in[19];
  const float* ln_g = (const float*)d_in[20];
  const float* ln_b = (const float*)d_in[21];
  float* out = (float*)d_out;

  float* ws = (float*)d_ws;
  size_t off = 0;
  auto alloc = [&](size_t n) {
    float* p = ws + off;
    off += (n + 3) & ~(size_t)3;
    return p;
  };
  auto allocU = [&](size_t n) { return (ushort*)alloc((n + 1) / 2); };

  // fp32 packed weights (small-M gemms)
  float* WCAT0Q = alloc(512 * 544);
  float* WCAT1K = alloc(512 * 544);
  float* BCAT0Q = alloc(544);
  float* BCAT1K = alloc(544);
  // bf16 transposed weights (big gemms)
  ushort* BT0K = allocU(640 * 512);
  ushort* BT1Q = allocU(640 * 512);
  ushort* BTV0 = allocU(512 * 512);
  ushort* BTO1 = allocU(512 * 512);
  float* B0K = alloc(544);
  float* B1Q = alloc(544);
  float* BV0 = alloc(512);
  float* BO1 = alloc(512);
  float* pen = alloc(16);
  float* QF0 = alloc(96 * 544);
  float* Qr0 = alloc(8 * 96 * 128);
  float* KF0 = alloc((size_t)24576 * 544);  // reused as QF1
  float* V0 = alloc((size_t)24576 * 512);
  float* attn0 = alloc(768 * 512);
  float* y0 = alloc(768 * 512);
  float* xind = alloc(768 * 512);
  float* KF1 = alloc(768 * 544);
  float* V1 = alloc(768 * 512);
  float* Kr1 = alloc((size_t)64 * 96 * 128);
  float* accP = alloc((size_t)64 * NSC * 96 * 64);
  float* sumP = alloc((size_t)64 * NSC * 96);
  ushort* XB1 = allocU((size_t)24576 * 512);  // keysB, then queriesB
  ushort* XB2 = allocU((size_t)24576 * 512);  // valuesB, then attn1 (bf16)
  float* QF1 = KF0;

  init_pen<<<1, 64, 0, stream>>>(pen);
  const int packBlocks = (512 * 544 + 255) / 256;
  pack_w<<<packBlocks, 256, 0, stream>>>(Wq, Wqo, Wqt, bq, bqo, bqt, WCAT0Q, BCAT0Q);
  pack_w<<<packBlocks, 256, 0, stream>>>(Wk + 262144, Wko + 8192, Wkt + 8192,
                                         bk + 512, bko + 16, bkt + 16, WCAT1K, BCAT1K);
  pack_wt_fused<<<(640 * 512 + 255) / 256, 256, 0, stream>>>(
      Wk, Wko, Wkt, bk, bko, bkt, BT0K, B0K);
  pack_wt_fused<<<(640 * 512 + 255) / 256, 256, 0, stream>>>(
      Wq + 262144, Wqo + 8192, Wqt + 8192, bq + 512, bqo + 16, bqt + 16, BT1Q, B1Q);
  pack_wt_plain<<<(512 * 512 + 255) / 256, 256, 0, stream>>>(Wv, bv, BTV0, BV0);
  pack_wt_plain<<<(512 * 512 + 255) / 256, 256, 0, stream>>>(Wo + 262144, bo + 512,
                                                             BTO1, BO1);
  const int castBlocks = (24576 * 512 / 8 + 255) / 256;
  cast_bf16<<<castBlocks, 256, 0, stream>>>(keys, XB1, 24576 * 512 / 8);
  cast_bf16<<<castBlocks, 256, 0, stream>>>(values, XB2, 24576 * 512 / 8);

  // ---- layer 0 ----
  gemm_bf16_mfma<<<dim3(5, 192), 256, 0, stream>>>(XB1, BT0K, B0K, KF0, 544, 544, 1);
  gemm_bf16_mfma<<<dim3(4, 192), 256, 0, stream>>>(XB2, BTV0, BV0, V0, 512, 512, 0);
  gemm_k512<<<dim3(9, 2), 256, 0, stream>>>(I, WCAT0Q, BCAT0Q, QF0, 96, 544, 1);
  build_qr0<<<96, 256, 0, stream>>>(QF0, Qr0);
  penalty<<<(96 * 16 + 255) / 256, 256, 0, stream>>>(QF0, 96, 1, 8.f, pen);
  penalty<<<(24576 * 16 + 255) / 256, 256, 0, stream>>>(KF0, 3072, 8, 1.f, pen);
  attn0_mfma<<<dim3(8, 8, 8), 256, 0, stream>>>(KF0, V0, Qr0, accP, sumP);
  attn0_stage2<<<dim3(96, 8), 256, 0, stream>>>(accP, sumP, attn0);
  gemm_k512<<<dim3(8, 12), 256, 0, stream>>>(attn0, Wo, bo, y0, 768, 512, 0);
  trend_norm<<<dim3(96, 8), 256, 0, stream>>>(y0, ln_g, ln_b, xind);

  // ---- layer 1 ----
  gemm_k512<<<dim3(9, 12), 256, 0, stream>>>(xind, WCAT1K, BCAT1K, KF1, 768, 544, 1);
  gemm_k512<<<dim3(8, 12), 256, 0, stream>>>(xind, Wv + 262144, bv + 512, V1, 768, 512, 0);
  build_kr1<<<768, 256, 0, stream>>>(KF1, Kr1);
  penalty<<<(768 * 16 + 255) / 256, 256, 0, stream>>>(KF1, 96, 8, 1.f, pen);
  cast_bf16<<<castBlocks, 256, 0, stream>>>(queries, XB1, 24576 * 512 / 8);
  gemm_bf16_mfma<<<dim3(5, 192), 256, 0, stream>>>(XB1, BT1Q, B1Q, QF1, 544, 544, 1);
  penalty<<<(24576 * 16 + 255) / 256, 256, 0, stream>>>(QF1, 3072, 8, 1.f, pen);
  attn1_mfma<<<dim3(48, 8, 8), 256, 0, stream>>>(QF1, Kr1, V1, XB2);
  gemm_bf16_mfma<<<dim3(4, 192), 256, 0, stream>>>(XB2, BTO1, BO1, out, 512, 512, 0);
  write_pen<<<1, 64, 0, stream>>>(pen, out);
}